// Round 1
// baseline (1992.780 us; speedup 1.0000x reference)
//
#include <hip/hip_runtime.h>
#include <hip/hip_bf16.h>
#include <cstdint>
#include <cstddef>

#define BATCH 8
#define FRAMES 128
#define TOK (BATCH*FRAMES)   // 1024
#define NM 60
#define VF 196
#define DD 256
#define EDIM 512
#define NSTATE 16
#define DTRANK 16
#define NLAYER 4

// ---------------------------------------------------------------------------
// Fused video CNN: conv1(3->32,3x3,SAME)+ReLU+maxpool2 -> LDS,
//                  conv2(32->64,3x3,SAME)+ReLU+maxpool2+mean -> feat(1024,64)
// one block per image, 256 threads, dynamic LDS = lds1[32][32][33] + ldsi[3][18][66]
// ---------------------------------------------------------------------------
#define LDS1_SZ (32*32*33)
#define LDSI_SZ (3*18*66)

__global__ __launch_bounds__(256) void cnn_fused(
    const float* __restrict__ video,
    const float* __restrict__ w1, const float* __restrict__ b1,
    const float* __restrict__ w2, const float* __restrict__ b2,
    float* __restrict__ feat)
{
  extern __shared__ float lds[];
  float* lds1 = lds;             // [ch][py][px] pitch 33
  float* ldsi = lds + LDS1_SZ;   // [ic][row18][col66], zero-padded borders
  const int img = blockIdx.x;
  const int t = threadIdx.x;
  const float* vin = video + (size_t)img * (3*64*64);

  const int pyl = t >> 5;   // 0..7 pooled row within strip
  const int px  = t & 31;   // pooled col

  // ---- phase 1: conv1 + relu + pool, 4 strips of 8 pooled rows ----
  for (int s = 0; s < 4; ++s) {
    __syncthreads();
    for (int i = t; i < LDSI_SZ; i += 256) {
      int c  = i % 66;
      int r  = (i / 66) % 18;
      int ic = i / (66*18);
      int gr = 16*s - 1 + r;
      int gc = c - 1;
      float v = 0.f;
      if (gr >= 0 && gr < 64 && gc >= 0 && gc < 64)
        v = vin[ic*4096 + gr*64 + gc];
      ldsi[i] = v;
    }
    __syncthreads();
    float inv[3][4][4];
#pragma unroll
    for (int ic = 0; ic < 3; ++ic)
#pragma unroll
      for (int r = 0; r < 4; ++r)
#pragma unroll
        for (int c = 0; c < 4; ++c)
          inv[ic][r][c] = ldsi[ic*(18*66) + (2*pyl + r)*66 + (2*px + c)];
    const int py = 8*s + pyl;
#pragma unroll 1
    for (int ch = 0; ch < 32; ++ch) {
      float a0=0.f, a1=0.f, a2=0.f, a3=0.f;
      const float* wch = w1 + ch*27;
#pragma unroll
      for (int ic = 0; ic < 3; ++ic)
#pragma unroll
        for (int dy = 0; dy < 3; ++dy)
#pragma unroll
          for (int dx = 0; dx < 3; ++dx) {
            float w = wch[ic*9 + dy*3 + dx];
            a0 = fmaf(w, inv[ic][dy  ][dx  ], a0);
            a1 = fmaf(w, inv[ic][dy  ][dx+1], a1);
            a2 = fmaf(w, inv[ic][dy+1][dx  ], a2);
            a3 = fmaf(w, inv[ic][dy+1][dx+1], a3);
          }
      float bb = b1[ch];
      a0 = fmaxf(a0+bb, 0.f); a1 = fmaxf(a1+bb, 0.f);
      a2 = fmaxf(a2+bb, 0.f); a3 = fmaxf(a3+bb, 0.f);
      lds1[ch*(32*33) + py*33 + px] = fmaxf(fmaxf(a0,a1), fmaxf(a2,a3));
    }
  }
  __syncthreads();

  // ---- phase 2: conv2 + relu + pool + mean ----
  const int ocg = __builtin_amdgcn_readfirstlane(t >> 6); // wave-uniform oc group
  const int ps  = t & 63;
  float msum[16];
#pragma unroll
  for (int j = 0; j < 16; ++j) msum[j] = 0.f;

#pragma unroll 1
  for (int k = 0; k < 4; ++k) {
    const int p  = ps + 64*k;          // pooled pixel 0..255
    const int qy = p >> 4, qx = p & 15;
    float acc[16][4];
#pragma unroll
    for (int j = 0; j < 16; ++j) { acc[j][0]=0.f; acc[j][1]=0.f; acc[j][2]=0.f; acc[j][3]=0.f; }
#pragma unroll 1
    for (int ic = 0; ic < 32; ++ic) {
      float in[4][4];
#pragma unroll
      for (int r = 0; r < 4; ++r) {
        int y = 2*qy - 1 + r;
        bool yok = (y >= 0) & (y < 32);
#pragma unroll
        for (int c = 0; c < 4; ++c) {
          int x = 2*qx - 1 + c;
          bool ok = yok & (x >= 0) & (x < 32);
          in[r][c] = ok ? lds1[ic*(32*33) + y*33 + x] : 0.f;
        }
      }
      const float* wb = w2 + (size_t)(ocg*16)*288 + ic*9;
#pragma unroll
      for (int j = 0; j < 16; ++j) {
        const float* w = wb + j*288;
        float q0=w[0],q1=w[1],q2=w[2],q3=w[3],q4=w[4],q5=w[5],q6=w[6],q7=w[7],q8=w[8];
        acc[j][0] += q0*in[0][0]+q1*in[0][1]+q2*in[0][2]+q3*in[1][0]+q4*in[1][1]+q5*in[1][2]+q6*in[2][0]+q7*in[2][1]+q8*in[2][2];
        acc[j][1] += q0*in[0][1]+q1*in[0][2]+q2*in[0][3]+q3*in[1][1]+q4*in[1][2]+q5*in[1][3]+q6*in[2][1]+q7*in[2][2]+q8*in[2][3];
        acc[j][2] += q0*in[1][0]+q1*in[1][1]+q2*in[1][2]+q3*in[2][0]+q4*in[2][1]+q5*in[2][2]+q6*in[3][0]+q7*in[3][1]+q8*in[3][2];
        acc[j][3] += q0*in[1][1]+q1*in[1][2]+q2*in[1][3]+q3*in[2][1]+q4*in[2][2]+q5*in[2][3]+q6*in[3][1]+q7*in[3][2]+q8*in[3][3];
      }
    }
#pragma unroll
    for (int j = 0; j < 16; ++j) {
      float bb = b2[ocg*16 + j];
      float v0 = fmaxf(acc[j][0]+bb, 0.f);
      float v1 = fmaxf(acc[j][1]+bb, 0.f);
      float v2 = fmaxf(acc[j][2]+bb, 0.f);
      float v3 = fmaxf(acc[j][3]+bb, 0.f);
      msum[j] += fmaxf(fmaxf(v0,v1), fmaxf(v2,v3));
    }
  }
#pragma unroll
  for (int j = 0; j < 16; ++j) {
#pragma unroll
    for (int off = 32; off; off >>= 1)
      msum[j] += __shfl_xor(msum[j], off, 64);
  }
  if ((t & 63) == 0) {
#pragma unroll
    for (int j = 0; j < 16; ++j)
      feat[img*64 + ocg*16 + j] = msum[j] * (1.f/256.f);
  }
}

// ---------------------------------------------------------------------------
// Generic f32 GEMM: C(M,N) = act(A(M,K) @ B(N,K)^T + bias) [+= C if resid]
// dual-direction via blockIdx.z. 64x64 tile, TK=16, 4x4 per-thread micro-tile.
// ---------------------------------------------------------------------------
struct GemmArgs {
  const float* A0; const float* A1;
  const float* B0; const float* B1;
  const float* bias0; const float* bias1;
  float* C0; float* C1;
  int M, N, K, lda, ldb, ldc, act, resid;
};

__global__ __launch_bounds__(256) void gemm_bt(GemmArgs g) {
  const int dir = blockIdx.z;
  const float* __restrict__ A = dir ? g.A1 : g.A0;
  const float* __restrict__ B = dir ? g.B1 : g.B0;
  const float* bias = dir ? g.bias1 : g.bias0;
  float* __restrict__ C = dir ? g.C1 : g.C0;
  __shared__ float sA[16][68];
  __shared__ float sB[16][68];
  const int t = threadIdx.x;
  const int m0 = blockIdx.x * 64;
  const int n0 = blockIdx.y * 64;
  const int tx = t & 15, ty = t >> 4;
  const int lk = t & 15, lr = t >> 4;
  float acc[4][4] = {};
  for (int k0 = 0; k0 < g.K; k0 += 16) {
    bool kok = (k0 + lk) < g.K;
#pragma unroll
    for (int rr = 0; rr < 4; ++rr) {
      int m = m0 + lr + rr*16;
      sA[lk][lr + rr*16] = (kok && m < g.M) ? A[(size_t)m*g.lda + k0 + lk] : 0.f;
      int n = n0 + lr + rr*16;
      sB[lk][lr + rr*16] = (kok && n < g.N) ? B[(size_t)n*g.ldb + k0 + lk] : 0.f;
    }
    __syncthreads();
#pragma unroll
    for (int kk = 0; kk < 16; ++kk) {
      float a0 = sA[kk][ty*4+0], a1 = sA[kk][ty*4+1], a2 = sA[kk][ty*4+2], a3 = sA[kk][ty*4+3];
      float b0 = sB[kk][tx*4+0], b1 = sB[kk][tx*4+1], b2 = sB[kk][tx*4+2], b3 = sB[kk][tx*4+3];
      acc[0][0]=fmaf(a0,b0,acc[0][0]); acc[0][1]=fmaf(a0,b1,acc[0][1]); acc[0][2]=fmaf(a0,b2,acc[0][2]); acc[0][3]=fmaf(a0,b3,acc[0][3]);
      acc[1][0]=fmaf(a1,b0,acc[1][0]); acc[1][1]=fmaf(a1,b1,acc[1][1]); acc[1][2]=fmaf(a1,b2,acc[1][2]); acc[1][3]=fmaf(a1,b3,acc[1][3]);
      acc[2][0]=fmaf(a2,b0,acc[2][0]); acc[2][1]=fmaf(a2,b1,acc[2][1]); acc[2][2]=fmaf(a2,b2,acc[2][2]); acc[2][3]=fmaf(a2,b3,acc[2][3]);
      acc[3][0]=fmaf(a3,b0,acc[3][0]); acc[3][1]=fmaf(a3,b1,acc[3][1]); acc[3][2]=fmaf(a3,b2,acc[3][2]); acc[3][3]=fmaf(a3,b3,acc[3][3]);
    }
    __syncthreads();
  }
#pragma unroll
  for (int i = 0; i < 4; ++i) {
    int m = m0 + ty*4 + i;
    if (m >= g.M) continue;
#pragma unroll
    for (int j = 0; j < 4; ++j) {
      int n = n0 + tx*4 + j;
      if (n >= g.N) continue;
      float v = acc[i][j];
      if (bias) v += bias[n];
      if (g.act == 1) v = v / (1.f + __expf(-v));                      // silu
      else if (g.act == 2) v = (v > 20.f) ? v : log1pf(expf(v));       // softplus
      size_t ci = (size_t)m * g.ldc + n;
      if (g.resid) v += C[ci];
      C[ci] = v;
    }
  }
}

// ---------------------------------------------------------------------------
// small kernels
// ---------------------------------------------------------------------------
__global__ void audio_concat(const float* __restrict__ audio, float* __restrict__ xc0) {
  int i = blockIdx.x*256 + threadIdx.x;
  if (i >= BATCH*FRAMES*NM) return;
  int j = i % NM; int f = (i / NM) % FRAMES; int b = i / (NM*FRAMES);
  xc0[(size_t)(b*FRAMES + f)*DD + VF + j] = audio[(size_t)b*(FRAMES*NM) + f*NM + j];
}

__global__ void copy_rev(const float* __restrict__ src, float* __restrict__ xf, float* __restrict__ xr) {
  int i = blockIdx.x*256 + threadIdx.x;
  if (i >= TOK*DD) return;
  int d = i % DD; int tok = i / DD; int b = tok / FRAMES; int l = tok % FRAMES;
  float v = src[i];
  xf[i] = v;
  xr[(size_t)(b*FRAMES + (FRAMES-1-l))*DD + d] = v;
}

__global__ __launch_bounds__(64) void rmsnorm_k(
    const float* __restrict__ xF, const float* __restrict__ xR,
    const float* __restrict__ wF, const float* __restrict__ wR,
    float* __restrict__ oF, float* __restrict__ oR)
{
  const int dir = blockIdx.y;
  const float* x = (dir ? xR : xF) + (size_t)blockIdx.x * DD;
  const float* w = dir ? wR : wF;
  float* o = (dir ? oR : oF) + (size_t)blockIdx.x * DD;
  int t = threadIdx.x;
  float v0 = x[t], v1 = x[t+64], v2 = x[t+128], v3 = x[t+192];
  float ss = v0*v0 + v1*v1 + v2*v2 + v3*v3;
#pragma unroll
  for (int off = 32; off; off >>= 1) ss += __shfl_xor(ss, off, 64);
  float r = rsqrtf(ss * (1.f/DD) + 1e-5f);
  o[t]     = v0*r*w[t];
  o[t+64]  = v1*r*w[t+64];
  o[t+128] = v2*r*w[t+128];
  o[t+192] = v3*r*w[t+192];
}

__global__ void convsilu_k(const float* __restrict__ xzF, const float* __restrict__ xzR,
                           const float* __restrict__ cwF, const float* __restrict__ cwR,
                           const float* __restrict__ cbF, const float* __restrict__ cbR,
                           float* __restrict__ oF, float* __restrict__ oR) {
  const int dir = blockIdx.z;
  const float* xz = dir ? xzR : xzF;
  const float* cw = dir ? cwR : cwF;
  const float* cb = dir ? cbR : cbF;
  float* o = dir ? oR : oF;
  int i = blockIdx.x*256 + threadIdx.x;
  if (i >= TOK*EDIM) return;
  int e   = i & (EDIM-1);
  int tok = i >> 9;
  int l   = tok & (FRAMES-1);
  float4 cv = ((const float4*)cw)[e];   // conv_w[e][0..3]
  float acc = cb[e];
  const float* xcol = xz + (size_t)tok*1024 + e;
  if (l >= 3) acc = fmaf(xcol[-3*1024], cv.x, acc);
  if (l >= 2) acc = fmaf(xcol[-2*1024], cv.y, acc);
  if (l >= 1) acc = fmaf(xcol[-1*1024], cv.z, acc);
  acc = fmaf(xcol[0], cv.w, acc);
  o[i] = acc / (1.f + __expf(-acc));    // silu
}

__global__ __launch_bounds__(256) void scan_k(
    const float* __restrict__ xzF, const float* __restrict__ xzR,
    const float* __restrict__ xcF, const float* __restrict__ xcR,
    const float* __restrict__ dbF, const float* __restrict__ dbR,
    const float* __restrict__ dlF, const float* __restrict__ dlR,
    const float* __restrict__ AlF, const float* __restrict__ AlR,
    const float* __restrict__ DpF, const float* __restrict__ DpR,
    float* __restrict__ yF, float* __restrict__ yR)
{
  const int dir = blockIdx.z;
  const float* xz = dir ? xzR : xzF;
  const float* xc = dir ? xcR : xcF;
  const float* db = dir ? dbR : dbF;
  const float* dl = dir ? dlR : dlF;
  const float* Al = dir ? AlR : AlF;
  const float* Dp = dir ? DpR : DpF;
  float* y = dir ? yR : yF;
  int i = blockIdx.x*256 + threadIdx.x;     // 0..4095 -> (b,e)
  int b = __builtin_amdgcn_readfirstlane(i >> 9);
  int e = i & (EDIM-1);
  float A[NSTATE];
#pragma unroll
  for (int n = 0; n < NSTATE; ++n) A[n] = -expf(Al[e*NSTATE + n]);
  float Dv = Dp[e];
  float h[NSTATE];
#pragma unroll
  for (int n = 0; n < NSTATE; ++n) h[n] = 0.f;
  const float* dlp = dl + (size_t)b*FRAMES*EDIM + e;
  const float* xcp = xc + (size_t)b*FRAMES*EDIM + e;
  const float* zp  = xz + (size_t)b*FRAMES*1024 + 512 + e;
  const float* dbp = db + (size_t)b*FRAMES*48;
  float* yp = y + (size_t)b*FRAMES*EDIM + e;
#pragma unroll 1
  for (int l = 0; l < FRAMES; ++l) {
    float dlt = dlp[(size_t)l*EDIM];
    float xcv = xcp[(size_t)l*EDIM];
    float zz  = zp[(size_t)l*1024];
    const float* dbt = dbp + l*48;
    float dx = dlt * xcv;
    float acc = 0.f;
#pragma unroll
    for (int n = 0; n < NSTATE; ++n) {
      float dA = __expf(dlt * A[n]);
      h[n] = fmaf(dA, h[n], dx * dbt[16+n]);
      acc = fmaf(h[n], dbt[32+n], acc);
    }
    acc = fmaf(Dv, xcv, acc);
    float sz = zz / (1.f + __expf(-zz));
    yp[(size_t)l*EDIM] = acc * sz;
  }
}

__global__ __launch_bounds__(256) void head_k(
    const float* __restrict__ xf, const float* __restrict__ xr,
    const float* __restrict__ fcw, const float* __restrict__ fcb,
    const float* __restrict__ fc2w, const float* __restrict__ fc2b,
    float* __restrict__ out)
{
  int b = blockIdx.x;
  __shared__ float xl[2*DD];
  __shared__ float h[DD];
  int t = threadIdx.x;
  xl[t]      = xf[(size_t)(b*FRAMES + FRAMES-1)*DD + t];   // fwd last frame
  xl[DD + t] = xr[(size_t)(b*FRAMES + 0)*DD + t];          // bwd (rev-seq frame 0)
  __syncthreads();
  float acc = fcb[t];
  for (int k = 0; k < 2*DD; ++k) acc = fmaf(xl[k], fcw[(size_t)t*2*DD + k], acc);
  h[t] = acc;
  __syncthreads();
  if (t < 2) {
    float a = fc2b[t];
    for (int k = 0; k < DD; ++k) a = fmaf(h[k], fc2w[(size_t)t*DD + k], a);
    out[b*2 + t] = a;
  }
}

// ---------------------------------------------------------------------------
extern "C" void kernel_launch(void* const* d_in, const int* in_sizes, int n_in,
                              void* d_out, int out_size, void* d_ws, size_t ws_size,
                              hipStream_t stream) {
  const float* video = (const float*)d_in[0];
  const float* audio = (const float*)d_in[1];
  const float* c1w = (const float*)d_in[2];
  const float* c1b = (const float*)d_in[3];
  const float* c2w = (const float*)d_in[4];
  const float* c2b = (const float*)d_in[5];
  const float* fcw = (const float*)d_in[6];
  const float* fcb = (const float*)d_in[7];
  const float* Wf[10]; const float* Wb[10];
  for (int i = 0; i < 10; ++i) { Wf[i] = (const float*)d_in[8+i]; Wb[i] = (const float*)d_in[18+i]; }
  const float* fc_w  = (const float*)d_in[28];
  const float* fc_b  = (const float*)d_in[29];
  const float* fc2_w = (const float*)d_in[30];
  const float* fc2_b = (const float*)d_in[31];
  float* out = (float*)d_out;

  // workspace layout (floats) — total 6,717,440 floats = 25.6 MiB
  float* ws   = (float*)d_ws;
  float* feat = ws;                 // 1024*64
  float* xc0  = feat + 65536;       // 1024*256
  float* xf   = xc0  + 262144;
  float* xr   = xf   + 262144;
  float* xnF  = xr   + 262144;
  float* xnR  = xnF  + 262144;
  float* xzF  = xnR  + 262144;      // 1024*1024
  float* xzR  = xzF  + 1048576;
  float* xvF  = xzR  + 1048576;     // xconv 1024*512
  float* xvR  = xvF  + 524288;
  float* dbF  = xvR  + 524288;      // 1024*48
  float* dbR  = dbF  + 49152;
  float* dlF  = dbR  + 49152;       // delta 1024*512
  float* dlR  = dlF  + 524288;
  float* ybF  = dlR  + 524288;      // y 1024*512
  float* ybR  = ybF  + 524288;

  // 1. fused CNN  (dynamic LDS 149.4 KB <= 160 KB/CU)
  size_t ldsB = (size_t)(LDS1_SZ + LDSI_SZ) * sizeof(float);
  cnn_fused<<<dim3(TOK), dim3(256), ldsB, stream>>>(video, c1w, c1b, c2w, c2b, feat);

  // 2. cnn fc: feat(1024,64) @ fcw(196,64)^T + fcb -> xc0 cols [0,196), ldc=256
  { GemmArgs g{feat, feat, fcw, fcw, fcb, fcb, xc0, xc0, TOK, VF, 64, 64, 64, DD, 0, 0};
    gemm_bt<<<dim3(16, 4, 1), 256, 0, stream>>>(g); }
  // 3. audio -> xc0 cols [196,256)
  audio_concat<<<dim3((BATCH*FRAMES*NM + 255)/256), 256, 0, stream>>>(audio, xc0);
  // 4. xf = xc0 ; xr = reverse_L(xc0)
  copy_rev<<<dim3((TOK*DD + 255)/256), 256, 0, stream>>>(xc0, xf, xr);

  // 5. bi-Mamba, fwd(dir0 on xf) and bwd(dir1 on xr) concurrently via blockIdx.z
  for (int l = 0; l < NLAYER; ++l) {
    const float* nwF  = Wf[0] + l*DD;            const float* nwR  = Wb[0] + l*DD;
    const float* ipF  = Wf[1] + (size_t)l*1024*DD; const float* ipR = Wb[1] + (size_t)l*1024*DD;
    const float* cwF_ = Wf[2] + l*EDIM*4;        const float* cwR_ = Wb[2] + l*EDIM*4;
    const float* cbF_ = Wf[3] + l*EDIM;          const float* cbR_ = Wb[3] + l*EDIM;
    const float* xpF  = Wf[4] + l*48*EDIM;       const float* xpR  = Wb[4] + l*48*EDIM;
    const float* dwF  = Wf[5] + l*EDIM*DTRANK;   const float* dwR  = Wb[5] + l*EDIM*DTRANK;
    const float* dbF_ = Wf[6] + l*EDIM;          const float* dbR_ = Wb[6] + l*EDIM;
    const float* AlF  = Wf[7] + l*EDIM*NSTATE;   const float* AlR  = Wb[7] + l*EDIM*NSTATE;
    const float* DpF  = Wf[8] + l*EDIM;          const float* DpR  = Wb[8] + l*EDIM;
    const float* opF  = Wf[9] + (size_t)l*DD*EDIM; const float* opR = Wb[9] + (size_t)l*DD*EDIM;

    rmsnorm_k<<<dim3(TOK, 2), 64, 0, stream>>>(xf, xr, nwF, nwR, xnF, xnR);
    { GemmArgs g{xnF, xnR, ipF, ipR, nullptr, nullptr, xzF, xzR, TOK, 1024, DD, DD, DD, 1024, 0, 0};
      gemm_bt<<<dim3(16,16,2), 256, 0, stream>>>(g); }
    convsilu_k<<<dim3(TOK*EDIM/256, 1, 2), 256, 0, stream>>>(xzF, xzR, cwF_, cwR_, cbF_, cbR_, xvF, xvR);
    { GemmArgs g{xvF, xvR, xpF, xpR, nullptr, nullptr, dbF, dbR, TOK, 48, EDIM, EDIM, EDIM, 48, 0, 0};
      gemm_bt<<<dim3(16,1,2), 256, 0, stream>>>(g); }
    { GemmArgs g{dbF, dbR, dwF, dwR, dbF_, dbR_, dlF, dlR, TOK, EDIM, DTRANK, 48, DTRANK, EDIM, 2, 0};
      gemm_bt<<<dim3(16,8,2), 256, 0, stream>>>(g); }
    scan_k<<<dim3(16,1,2), 256, 0, stream>>>(xzF, xzR, xvF, xvR, dbF, dbR, dlF, dlR, AlF, AlR, DpF, DpR, ybF, ybR);
    { GemmArgs g{ybF, ybR, opF, opR, nullptr, nullptr, xf, xr, TOK, DD, EDIM, EDIM, EDIM, DD, 0, 1};
      gemm_bt<<<dim3(16,4,2), 256, 0, stream>>>(g); }
  }

  // 6. head: concat(xf[:,127,:], xr[:,0,:]) -> fc -> fc2 -> out(8,2)
  head_k<<<dim3(BATCH), 256, 0, stream>>>(xf, xr, fc_w, fc_b, fc2_w, fc2_b, out);
}

// Round 2
// 1287.943 us; speedup vs baseline: 1.5473x; 1.5473x over previous
//
#include <hip/hip_runtime.h>
#include <hip/hip_bf16.h>
#include <cstdint>
#include <cstddef>

#define BATCH 8
#define FRAMES 128
#define TOK (BATCH*FRAMES)   // 1024
#define NM 60
#define VF 196
#define DD 256
#define EDIM 512
#define NSTATE 16
#define DTRANK 16
#define NLAYER 4

typedef __attribute__((ext_vector_type(8))) short short8v;
typedef __attribute__((ext_vector_type(4))) float f32x4;

__device__ __forceinline__ unsigned short f2bf(float f) {
  unsigned x = __float_as_uint(f);
  unsigned r = (x + 0x7FFFu + ((x >> 16) & 1u)) >> 16;
  return (unsigned short)r;
}

// ---------------------------------------------------------------------------
// pack_w2: W2 (64,32,3,3) f32 -> Wb[shift(9)][mtile(4)][lane(64)][8] bf16
// laid out exactly as the 16x16x32 MFMA A-fragment wants.
// ---------------------------------------------------------------------------
__global__ void pack_w2(const float* __restrict__ w2, unsigned short* __restrict__ Wb) {
  int id = blockIdx.x * 256 + threadIdx.x;     // 0..2303
  if (id >= 9 * 4 * 64) return;
  int lane = id & 63;
  int mt = (id >> 6) & 3;
  int sh = id >> 8;
  int dy = sh / 3, dx = sh % 3;
  int oc = mt * 16 + (lane & 15);
  int ic0 = (lane >> 4) * 8;
  unsigned u[4];
#pragma unroll
  for (int p = 0; p < 4; ++p) {
    unsigned short lo = f2bf(w2[((oc * 32 + ic0 + 2 * p) * 3 + dy) * 3 + dx]);
    unsigned short hi = f2bf(w2[((oc * 32 + ic0 + 2 * p + 1) * 3 + dy) * 3 + dx]);
    u[p] = (unsigned)lo | ((unsigned)hi << 16);
  }
  uint4 v = {u[0], u[1], u[2], u[3]};
  *(uint4*)(Wb + (size_t)id * 8) = v;
}

// ---------------------------------------------------------------------------
// conv1_k: conv(3->32,3x3,SAME)+bias+ReLU+maxpool2 per image.
// One block = one image. Static LDS ~60.7KB -> 2 blocks/CU.
// Output: X1 bf16 [img][y(32)][x(32)][ic(32)]
// ---------------------------------------------------------------------------
#define C1_PITCH 72
#define C1_ROWS 66
__global__ __launch_bounds__(256) void conv1_k(
    const float* __restrict__ video, const float* __restrict__ w1,
    const float* __restrict__ b1, unsigned short* __restrict__ X1)
{
  __shared__ float imgs[3 * C1_ROWS * C1_PITCH];   // zero-padded, data at rows 1..64, cols 4..67
  __shared__ float wsm[32 * 28];
  __shared__ float bsm[32];
  const int img = blockIdx.x, t = threadIdx.x;
  const float* vin = video + (size_t)img * (3 * 64 * 64);

  float4 z4 = {0.f, 0.f, 0.f, 0.f};
  for (int i = t; i < (3 * C1_ROWS * C1_PITCH) / 4; i += 256) ((float4*)imgs)[i] = z4;
  for (int i = t; i < 32 * 28; i += 256) wsm[i] = ((i % 28) < 27) ? w1[(i / 28) * 27 + (i % 28)] : 0.f;
  if (t < 32) bsm[t] = b1[t];
  __syncthreads();
#pragma unroll 4
  for (int i = 0; i < 12; ++i) {
    int c = i * 256 + t;           // float4 chunk, 3072 total
    int g = c * 4;
    int ic = g >> 12; int rem = g & 4095; int gy = rem >> 6; int gx = rem & 63;
    float4 v = *(const float4*)(vin + g);
    *(float4*)(imgs + ic * (C1_ROWS * C1_PITCH) + (gy + 1) * C1_PITCH + gx + 4) = v;
  }
  __syncthreads();

  const int px = t & 31, pyl = t >> 5;
#pragma unroll 1
  for (int s = 0; s < 4; ++s) {
    const int y = pyl + 8 * s;     // pooled row
    float in[3][4][4];
#pragma unroll
    for (int ic = 0; ic < 3; ++ic)
#pragma unroll
      for (int rr = 0; rr < 4; ++rr)
#pragma unroll
        for (int cc = 0; cc < 4; ++cc)
          in[ic][rr][cc] = imgs[ic * (C1_ROWS * C1_PITCH) + (2 * y + rr) * C1_PITCH + (2 * px + 3 + cc)];
    unsigned ob[16];
#pragma unroll
    for (int ch = 0; ch < 32; ++ch) {
      float wv[28];
#pragma unroll
      for (int q = 0; q < 7; ++q)
        *(float4*)(wv + 4 * q) = *(const float4*)(wsm + ch * 28 + 4 * q);
      float bb = bsm[ch];
      float a0 = bb, a1 = bb, a2 = bb, a3 = bb;
#pragma unroll
      for (int ic = 0; ic < 3; ++ic)
#pragma unroll
        for (int dy = 0; dy < 3; ++dy)
#pragma unroll
          for (int dx = 0; dx < 3; ++dx) {
            float w = wv[ic * 9 + dy * 3 + dx];
            a0 = fmaf(w, in[ic][dy    ][dx    ], a0);
            a1 = fmaf(w, in[ic][dy    ][dx + 1], a1);
            a2 = fmaf(w, in[ic][dy + 1][dx    ], a2);
            a3 = fmaf(w, in[ic][dy + 1][dx + 1], a3);
          }
      a0 = fmaxf(a0, 0.f); a1 = fmaxf(a1, 0.f);
      a2 = fmaxf(a2, 0.f); a3 = fmaxf(a3, 0.f);
      float pooled = fmaxf(fmaxf(a0, a1), fmaxf(a2, a3));
      unsigned short u = f2bf(pooled);
      if ((ch & 1) == 0) ob[ch >> 1] = (unsigned)u;
      else               ob[ch >> 1] |= ((unsigned)u << 16);
    }
    size_t base = ((size_t)img * 1024 + (size_t)y * 32 + px) * 32;  // ushort index
    uint4 o0 = {ob[0], ob[1], ob[2], ob[3]};
    uint4 o1 = {ob[4], ob[5], ob[6], ob[7]};
    uint4 o2 = {ob[8], ob[9], ob[10], ob[11]};
    uint4 o3 = {ob[12], ob[13], ob[14], ob[15]};
    uint4* dst = (uint4*)(X1 + base);
    dst[0] = o0; dst[1] = o1; dst[2] = o2; dst[3] = o3;
  }
}

// ---------------------------------------------------------------------------
// conv2_k: implicit-GEMM conv(32->64,3x3,SAME)+bias+ReLU+maxpool2+mean via MFMA.
// One block = one image, 4 waves. LDS X layout: [oct(4)][P'(34*34)][8ic=16B].
// Each wave: M=64 x N=256 pixels (2 passes of 128), 9 shifts x K=32.
// ---------------------------------------------------------------------------
#define X_LDS_BYTES (4 * 1156 * 16)   // 73984
#define OCT_STRIDE  (1156 * 16)       // 18496 bytes
__global__ __launch_bounds__(256) void conv2_k(
    const unsigned short* __restrict__ X1, const unsigned short* __restrict__ Wb,
    const float* __restrict__ b2, float* __restrict__ feat)
{
  extern __shared__ char sm[];
  float* part = (float*)(sm + X_LDS_BYTES);   // 256 floats
  const int img = blockIdx.x, t = threadIdx.x;
  const int lane = t & 63, wv = t >> 6;
  const int kg = lane >> 4, l15 = lane & 15;

  // zero padded border (rows 0,33 cols 0,33 of the 34x34 grid, all 4 octets)
  for (int j = t; j < 1156; j += 256) {
    int r = j / 34, cc = j - r * 34;
    if (r == 0 || r == 33 || cc == 0 || cc == 33) {
      uint4 z = {0, 0, 0, 0};
#pragma unroll
      for (int oct = 0; oct < 4; ++oct)
        *(uint4*)(sm + oct * OCT_STRIDE + j * 16) = z;
    }
  }
  // stage interior: global [P][oct] chunks -> LDS [oct][P'] (reg-staged permute)
  const uint4* src = (const uint4*)(X1 + (size_t)img * 32768);
#pragma unroll 4
  for (int i = 0; i < 16; ++i) {
    int c = i * 256 + t;             // 4096 chunks of 16B
    uint4 v = src[c];
    int oct = c & 3, P = c >> 2;
    int y = P >> 5, x = P & 31;
    *(uint4*)(sm + oct * OCT_STRIDE + ((y + 1) * 34 + (x + 1)) * 16) = v;
  }
  __syncthreads();

  float bia[4][4];
#pragma unroll
  for (int mt = 0; mt < 4; ++mt)
#pragma unroll
    for (int r = 0; r < 4; ++r) bia[mt][r] = b2[mt * 16 + kg * 4 + r];

  float msum[4][4];
#pragma unroll
  for (int mt = 0; mt < 4; ++mt)
#pragma unroll
    for (int r = 0; r < 4; ++r) msum[mt][r] = 0.f;

#pragma unroll 1
  for (int pass = 0; pass < 2; ++pass) {
    f32x4 acc[4][8];
#pragma unroll
    for (int mt = 0; mt < 4; ++mt)
#pragma unroll
      for (int q = 0; q < 8; ++q) acc[mt][q] = (f32x4){0.f, 0.f, 0.f, 0.f};

    int Pq[8];
#pragma unroll
    for (int q = 0; q < 8; ++q) {
      int p = (wv * 16 + pass * 8 + q) * 16 + l15;   // pixel 0..1023
      int y = p >> 5, x = p & 31;
      Pq[q] = y * 34 + x;                            // P' base (dy=dx=0)
    }
#pragma unroll
    for (int sh = 0; sh < 9; ++sh) {
      const int dy = sh / 3, dx = sh % 3;
      const int shoff = (dy * 34 + dx) * 16;
      short8v Af[4];
#pragma unroll
      for (int mt = 0; mt < 4; ++mt)
        Af[mt] = *(const short8v*)(Wb + ((size_t)(sh * 4 + mt) * 64 + lane) * 8);
#pragma unroll
      for (int q = 0; q < 8; ++q) {
        short8v Bf = *(const short8v*)(sm + kg * OCT_STRIDE + Pq[q] * 16 + shoff);
#pragma unroll
        for (int mt = 0; mt < 4; ++mt)
          acc[mt][q] = __builtin_amdgcn_mfma_f32_16x16x32_bf16(Af[mt], Bf, acc[mt][q], 0, 0, 0);
      }
    }
    // epilogue: bias + relu + 2x2 maxpool + accumulate mean partials
#pragma unroll
    for (int mt = 0; mt < 4; ++mt) {
#pragma unroll
      for (int pr = 0; pr < 4; ++pr) {
        int qa = (pr & 1) + (pr >> 1) * 4;   // 0,1,4,5
        int qb = qa + 2;
#pragma unroll
        for (int r = 0; r < 4; ++r) {
          float va = fmaxf(acc[mt][qa][r] + bia[mt][r], 0.f);
          float vb = fmaxf(acc[mt][qb][r] + bia[mt][r], 0.f);
          float v = fmaxf(va, vb);
          v = fmaxf(v, __shfl_xor(v, 1, 64));   // pool across x-pairs (lane pairs)
          msum[mt][r] += v;                      // each pooled value counted twice
        }
      }
    }
  }
  // reduce across the 16 lanes of each kg-group (includes the x2 duplication)
#pragma unroll
  for (int mt = 0; mt < 4; ++mt)
#pragma unroll
    for (int r = 0; r < 4; ++r) {
      float v = msum[mt][r];
      v += __shfl_xor(v, 1, 64);
      v += __shfl_xor(v, 2, 64);
      v += __shfl_xor(v, 4, 64);
      v += __shfl_xor(v, 8, 64);
      if (l15 == 0) part[wv * 64 + mt * 16 + kg * 4 + r] = v * 0.5f;
    }
  __syncthreads();
  if (t < 64)
    feat[(size_t)img * 64 + t] =
        (part[t] + part[64 + t] + part[128 + t] + part[192 + t]) * (1.f / 256.f);
}

// ---------------------------------------------------------------------------
// Generic f32 GEMM: C(M,N) = act(A(M,K) @ B(N,K)^T + bias) [+= C if resid]
// ---------------------------------------------------------------------------
struct GemmArgs {
  const float* A0; const float* A1;
  const float* B0; const float* B1;
  const float* bias0; const float* bias1;
  float* C0; float* C1;
  int M, N, K, lda, ldb, ldc, act, resid;
};

__global__ __launch_bounds__(256) void gemm_bt(GemmArgs g) {
  const int dir = blockIdx.z;
  const float* __restrict__ A = dir ? g.A1 : g.A0;
  const float* __restrict__ B = dir ? g.B1 : g.B0;
  const float* bias = dir ? g.bias1 : g.bias0;
  float* __restrict__ C = dir ? g.C1 : g.C0;
  __shared__ float sA[16][68];
  __shared__ float sB[16][68];
  const int t = threadIdx.x;
  const int m0 = blockIdx.x * 64;
  const int n0 = blockIdx.y * 64;
  const int tx = t & 15, ty = t >> 4;
  const int lk = t & 15, lr = t >> 4;
  float acc[4][4] = {};
  for (int k0 = 0; k0 < g.K; k0 += 16) {
    bool kok = (k0 + lk) < g.K;
#pragma unroll
    for (int rr = 0; rr < 4; ++rr) {
      int m = m0 + lr + rr*16;
      sA[lk][lr + rr*16] = (kok && m < g.M) ? A[(size_t)m*g.lda + k0 + lk] : 0.f;
      int n = n0 + lr + rr*16;
      sB[lk][lr + rr*16] = (kok && n < g.N) ? B[(size_t)n*g.ldb + k0 + lk] : 0.f;
    }
    __syncthreads();
#pragma unroll
    for (int kk = 0; kk < 16; ++kk) {
      float a0 = sA[kk][ty*4+0], a1 = sA[kk][ty*4+1], a2 = sA[kk][ty*4+2], a3 = sA[kk][ty*4+3];
      float b0 = sB[kk][tx*4+0], b1 = sB[kk][tx*4+1], b2 = sB[kk][tx*4+2], b3 = sB[kk][tx*4+3];
      acc[0][0]=fmaf(a0,b0,acc[0][0]); acc[0][1]=fmaf(a0,b1,acc[0][1]); acc[0][2]=fmaf(a0,b2,acc[0][2]); acc[0][3]=fmaf(a0,b3,acc[0][3]);
      acc[1][0]=fmaf(a1,b0,acc[1][0]); acc[1][1]=fmaf(a1,b1,acc[1][1]); acc[1][2]=fmaf(a1,b2,acc[1][2]); acc[1][3]=fmaf(a1,b3,acc[1][3]);
      acc[2][0]=fmaf(a2,b0,acc[2][0]); acc[2][1]=fmaf(a2,b1,acc[2][1]); acc[2][2]=fmaf(a2,b2,acc[2][2]); acc[2][3]=fmaf(a2,b3,acc[2][3]);
      acc[3][0]=fmaf(a3,b0,acc[3][0]); acc[3][1]=fmaf(a3,b1,acc[3][1]); acc[3][2]=fmaf(a3,b2,acc[3][2]); acc[3][3]=fmaf(a3,b3,acc[3][3]);
    }
    __syncthreads();
  }
#pragma unroll
  for (int i = 0; i < 4; ++i) {
    int m = m0 + ty*4 + i;
    if (m >= g.M) continue;
#pragma unroll
    for (int j = 0; j < 4; ++j) {
      int n = n0 + tx*4 + j;
      if (n >= g.N) continue;
      float v = acc[i][j];
      if (bias) v += bias[n];
      if (g.act == 1) v = v / (1.f + __expf(-v));
      else if (g.act == 2) v = (v > 20.f) ? v : log1pf(expf(v));
      size_t ci = (size_t)m * g.ldc + n;
      if (g.resid) v += C[ci];
      C[ci] = v;
    }
  }
}

// ---------------------------------------------------------------------------
// small kernels (unchanged from round 1)
// ---------------------------------------------------------------------------
__global__ void audio_concat(const float* __restrict__ audio, float* __restrict__ xc0) {
  int i = blockIdx.x*256 + threadIdx.x;
  if (i >= BATCH*FRAMES*NM) return;
  int j = i % NM; int f = (i / NM) % FRAMES; int b = i / (NM*FRAMES);
  xc0[(size_t)(b*FRAMES + f)*DD + VF + j] = audio[(size_t)b*(FRAMES*NM) + f*NM + j];
}

__global__ void copy_rev(const float* __restrict__ src, float* __restrict__ xf, float* __restrict__ xr) {
  int i = blockIdx.x*256 + threadIdx.x;
  if (i >= TOK*DD) return;
  int d = i % DD; int tok = i / DD; int b = tok / FRAMES; int l = tok % FRAMES;
  float v = src[i];
  xf[i] = v;
  xr[(size_t)(b*FRAMES + (FRAMES-1-l))*DD + d] = v;
}

__global__ __launch_bounds__(64) void rmsnorm_k(
    const float* __restrict__ xF, const float* __restrict__ xR,
    const float* __restrict__ wF, const float* __restrict__ wR,
    float* __restrict__ oF, float* __restrict__ oR)
{
  const int dir = blockIdx.y;
  const float* x = (dir ? xR : xF) + (size_t)blockIdx.x * DD;
  const float* w = dir ? wR : wF;
  float* o = (dir ? oR : oF) + (size_t)blockIdx.x * DD;
  int t = threadIdx.x;
  float v0 = x[t], v1 = x[t+64], v2 = x[t+128], v3 = x[t+192];
  float ss = v0*v0 + v1*v1 + v2*v2 + v3*v3;
#pragma unroll
  for (int off = 32; off; off >>= 1) ss += __shfl_xor(ss, off, 64);
  float r = rsqrtf(ss * (1.f/DD) + 1e-5f);
  o[t]     = v0*r*w[t];
  o[t+64]  = v1*r*w[t+64];
  o[t+128] = v2*r*w[t+128];
  o[t+192] = v3*r*w[t+192];
}

__global__ void convsilu_k(const float* __restrict__ xzF, const float* __restrict__ xzR,
                           const float* __restrict__ cwF, const float* __restrict__ cwR,
                           const float* __restrict__ cbF, const float* __restrict__ cbR,
                           float* __restrict__ oF, float* __restrict__ oR) {
  const int dir = blockIdx.z;
  const float* xz = dir ? xzR : xzF;
  const float* cw = dir ? cwR : cwF;
  const float* cb = dir ? cbR : cbF;
  float* o = dir ? oR : oF;
  int i = blockIdx.x*256 + threadIdx.x;
  if (i >= TOK*EDIM) return;
  int e   = i & (EDIM-1);
  int tok = i >> 9;
  int l   = tok & (FRAMES-1);
  float4 cv = ((const float4*)cw)[e];
  float acc = cb[e];
  const float* xcol = xz + (size_t)tok*1024 + e;
  if (l >= 3) acc = fmaf(xcol[-3*1024], cv.x, acc);
  if (l >= 2) acc = fmaf(xcol[-2*1024], cv.y, acc);
  if (l >= 1) acc = fmaf(xcol[-1*1024], cv.z, acc);
  acc = fmaf(xcol[0], cv.w, acc);
  o[i] = acc / (1.f + __expf(-acc));
}

__global__ __launch_bounds__(256) void scan_k(
    const float* __restrict__ xzF, const float* __restrict__ xzR,
    const float* __restrict__ xcF, const float* __restrict__ xcR,
    const float* __restrict__ dbF, const float* __restrict__ dbR,
    const float* __restrict__ dlF, const float* __restrict__ dlR,
    const float* __restrict__ AlF, const float* __restrict__ AlR,
    const float* __restrict__ DpF, const float* __restrict__ DpR,
    float* __restrict__ yF, float* __restrict__ yR)
{
  const int dir = blockIdx.z;
  const float* xz = dir ? xzR : xzF;
  const float* xc = dir ? xcR : xcF;
  const float* db = dir ? dbR : dbF;
  const float* dl = dir ? dlR : dlF;
  const float* Al = dir ? AlR : AlF;
  const float* Dp = dir ? DpR : DpF;
  float* y = dir ? yR : yF;
  int i = blockIdx.x*256 + threadIdx.x;
  int b = __builtin_amdgcn_readfirstlane(i >> 9);
  int e = i & (EDIM-1);
  float A[NSTATE];
#pragma unroll
  for (int n = 0; n < NSTATE; ++n) A[n] = -expf(Al[e*NSTATE + n]);
  float Dv = Dp[e];
  float h[NSTATE];
#pragma unroll
  for (int n = 0; n < NSTATE; ++n) h[n] = 0.f;
  const float* dlp = dl + (size_t)b*FRAMES*EDIM + e;
  const float* xcp = xc + (size_t)b*FRAMES*EDIM + e;
  const float* zp  = xz + (size_t)b*FRAMES*1024 + 512 + e;
  const float* dbp = db + (size_t)b*FRAMES*48;
  float* yp = y + (size_t)b*FRAMES*EDIM + e;
#pragma unroll 1
  for (int l = 0; l < FRAMES; ++l) {
    float dlt = dlp[(size_t)l*EDIM];
    float xcv = xcp[(size_t)l*EDIM];
    float zz  = zp[(size_t)l*1024];
    const float* dbt = dbp + l*48;
    float dx = dlt * xcv;
    float acc = 0.f;
#pragma unroll
    for (int n = 0; n < NSTATE; ++n) {
      float dA = __expf(dlt * A[n]);
      h[n] = fmaf(dA, h[n], dx * dbt[16+n]);
      acc = fmaf(h[n], dbt[32+n], acc);
    }
    acc = fmaf(Dv, xcv, acc);
    float sz = zz / (1.f + __expf(-zz));
    yp[(size_t)l*EDIM] = acc * sz;
  }
}

__global__ __launch_bounds__(256) void head_k(
    const float* __restrict__ xf, const float* __restrict__ xr,
    const float* __restrict__ fcw, const float* __restrict__ fcb,
    const float* __restrict__ fc2w, const float* __restrict__ fc2b,
    float* __restrict__ out)
{
  int b = blockIdx.x;
  __shared__ float xl[2*DD];
  __shared__ float h[DD];
  int t = threadIdx.x;
  xl[t]      = xf[(size_t)(b*FRAMES + FRAMES-1)*DD + t];
  xl[DD + t] = xr[(size_t)(b*FRAMES + 0)*DD + t];
  __syncthreads();
  float acc = fcb[t];
  for (int k = 0; k < 2*DD; ++k) acc = fmaf(xl[k], fcw[(size_t)t*2*DD + k], acc);
  h[t] = acc;
  __syncthreads();
  if (t < 2) {
    float a = fc2b[t];
    for (int k = 0; k < DD; ++k) a = fmaf(h[k], fc2w[(size_t)t*DD + k], a);
    out[b*2 + t] = a;
  }
}

// ---------------------------------------------------------------------------
extern "C" void kernel_launch(void* const* d_in, const int* in_sizes, int n_in,
                              void* d_out, int out_size, void* d_ws, size_t ws_size,
                              hipStream_t stream) {
  const float* video = (const float*)d_in[0];
  const float* audio = (const float*)d_in[1];
  const float* c1w = (const float*)d_in[2];
  const float* c1b = (const float*)d_in[3];
  const float* c2w = (const float*)d_in[4];
  const float* c2b = (const float*)d_in[5];
  const float* fcw = (const float*)d_in[6];
  const float* fcb = (const float*)d_in[7];
  const float* Wf[10]; const float* Wb_[10];
  for (int i = 0; i < 10; ++i) { Wf[i] = (const float*)d_in[8+i]; Wb_[i] = (const float*)d_in[18+i]; }
  const float* fc_w  = (const float*)d_in[28];
  const float* fc_b  = (const float*)d_in[29];
  const float* fc2_w = (const float*)d_in[30];
  const float* fc2_b = (const float*)d_in[31];
  float* out = (float*)d_out;

  // workspace layout (floats): mamba region [0, 6717440) as round 1,
  // then X1 (33.55M bf16 = 16.78M float-slots), then Wb pack (36KB).
  float* ws   = (float*)d_ws;
  float* feat = ws;                 // 1024*64
  float* xc0  = feat + 65536;
  float* xf   = xc0  + 262144;
  float* xr   = xf   + 262144;
  float* xnF  = xr   + 262144;
  float* xnR  = xnF  + 262144;
  float* xzF  = xnR  + 262144;
  float* xzR  = xzF  + 1048576;
  float* xvF  = xzR  + 1048576;
  float* xvR  = xvF  + 524288;
  float* dbF  = xvR  + 524288;
  float* dbR  = dbF  + 49152;
  float* dlF  = dbR  + 49152;
  float* dlR  = dlF  + 524288;
  float* ybF  = dlR  + 524288;
  float* ybR  = ybF  + 524288;
  unsigned short* X1 = (unsigned short*)(ws + 6717440);          // 1024*32*32*32 bf16
  unsigned short* Wbp = (unsigned short*)(ws + 6717440 + 16777216); // 9*4*64*8 bf16

  // 1. CNN
  pack_w2<<<dim3(9), 256, 0, stream>>>(c2w, Wbp);
  conv1_k<<<dim3(TOK), 256, 0, stream>>>(video, c1w, c1b, X1);
  conv2_k<<<dim3(TOK), 256, (size_t)(X_LDS_BYTES + 1024), stream>>>(X1, Wbp, c2b, feat);

  // 2. cnn fc
  { GemmArgs g{feat, feat, fcw, fcw, fcb, fcb, xc0, xc0, TOK, VF, 64, 64, 64, DD, 0, 0};
    gemm_bt<<<dim3(16, 4, 1), 256, 0, stream>>>(g); }
  audio_concat<<<dim3((BATCH*FRAMES*NM + 255)/256), 256, 0, stream>>>(audio, xc0);
  copy_rev<<<dim3((TOK*DD + 255)/256), 256, 0, stream>>>(xc0, xf, xr);

  // 3. bi-Mamba
  for (int l = 0; l < NLAYER; ++l) {
    const float* nwF  = Wf[0] + l*DD;              const float* nwR  = Wb_[0] + l*DD;
    const float* ipF  = Wf[1] + (size_t)l*1024*DD; const float* ipR  = Wb_[1] + (size_t)l*1024*DD;
    const float* cwF_ = Wf[2] + l*EDIM*4;          const float* cwR_ = Wb_[2] + l*EDIM*4;
    const float* cbF_ = Wf[3] + l*EDIM;            const float* cbR_ = Wb_[3] + l*EDIM;
    const float* xpF  = Wf[4] + l*48*EDIM;         const float* xpR  = Wb_[4] + l*48*EDIM;
    const float* dwF  = Wf[5] + l*EDIM*DTRANK;     const float* dwR  = Wb_[5] + l*EDIM*DTRANK;
    const float* dbF_ = Wf[6] + l*EDIM;            const float* dbR_ = Wb_[6] + l*EDIM;
    const float* AlF  = Wf[7] + l*EDIM*NSTATE;     const float* AlR  = Wb_[7] + l*EDIM*NSTATE;
    const float* DpF  = Wf[8] + l*EDIM;            const float* DpR  = Wb_[8] + l*EDIM;
    const float* opF  = Wf[9] + (size_t)l*DD*EDIM; const float* opR  = Wb_[9] + (size_t)l*DD*EDIM;

    rmsnorm_k<<<dim3(TOK, 2), 64, 0, stream>>>(xf, xr, nwF, nwR, xnF, xnR);
    { GemmArgs g{xnF, xnR, ipF, ipR, nullptr, nullptr, xzF, xzR, TOK, 1024, DD, DD, DD, 1024, 0, 0};
      gemm_bt<<<dim3(16,16,2), 256, 0, stream>>>(g); }
    convsilu_k<<<dim3(TOK*EDIM/256, 1, 2), 256, 0, stream>>>(xzF, xzR, cwF_, cwR_, cbF_, cbR_, xvF, xvR);
    { GemmArgs g{xvF, xvR, xpF, xpR, nullptr, nullptr, dbF, dbR, TOK, 48, EDIM, EDIM, EDIM, 48, 0, 0};
      gemm_bt<<<dim3(16,1,2), 256, 0, stream>>>(g); }
    { GemmArgs g{dbF, dbR, dwF, dwR, dbF_, dbR_, dlF, dlR, TOK, EDIM, DTRANK, 48, DTRANK, EDIM, 2, 0};
      gemm_bt<<<dim3(16,8,2), 256, 0, stream>>>(g); }
    scan_k<<<dim3(16,1,2), 256, 0, stream>>>(xzF, xzR, xvF, xvR, dbF, dbR, dlF, dlR, AlF, AlR, DpF, DpR, ybF, ybR);
    { GemmArgs g{ybF, ybR, opF, opR, nullptr, nullptr, xf, xr, TOK, DD, EDIM, EDIM, EDIM, DD, 0, 1};
      gemm_bt<<<dim3(16,4,2), 256, 0, stream>>>(g); }
  }

  // 4. head
  head_k<<<dim3(BATCH), 256, 0, stream>>>(xf, xr, fc_w, fc_b, fc2_w, fc2_b, out);
}

// Round 3
// 1262.190 us; speedup vs baseline: 1.5788x; 1.0204x over previous
//
#include <hip/hip_runtime.h>
#include <hip/hip_bf16.h>
#include <cstdint>
#include <cstddef>

#define BATCH 8
#define FRAMES 128
#define TOK (BATCH*FRAMES)   // 1024
#define NM 60
#define VF 196
#define DD 256
#define EDIM 512
#define NSTATE 16
#define DTRANK 16
#define NLAYER 4

typedef __attribute__((ext_vector_type(8))) short short8v;
typedef __attribute__((ext_vector_type(4))) float f32x4;

__device__ __forceinline__ unsigned short f2bf(float f) {
  unsigned x = __float_as_uint(f);
  unsigned r = (x + 0x7FFFu + ((x >> 16) & 1u)) >> 16;
  return (unsigned short)r;
}

// ---------------------------------------------------------------------------
// pack_w2: W2 (64,32,3,3) f32 -> Wb[shift(9)][mtile(4)][lane(64)][8] bf16
// ---------------------------------------------------------------------------
__global__ void pack_w2(const float* __restrict__ w2, unsigned short* __restrict__ Wb) {
  int id = blockIdx.x * 256 + threadIdx.x;
  if (id >= 9 * 4 * 64) return;
  int lane = id & 63;
  int mt = (id >> 6) & 3;
  int sh = id >> 8;
  int dy = sh / 3, dx = sh % 3;
  int oc = mt * 16 + (lane & 15);
  int ic0 = (lane >> 4) * 8;
  unsigned u[4];
#pragma unroll
  for (int p = 0; p < 4; ++p) {
    unsigned short lo = f2bf(w2[((oc * 32 + ic0 + 2 * p) * 3 + dy) * 3 + dx]);
    unsigned short hi = f2bf(w2[((oc * 32 + ic0 + 2 * p + 1) * 3 + dy) * 3 + dx]);
    u[p] = (unsigned)lo | ((unsigned)hi << 16);
  }
  uint4 v = {u[0], u[1], u[2], u[3]};
  *(uint4*)(Wb + (size_t)id * 8) = v;
}

// ---------------------------------------------------------------------------
// conv1_k: conv(3->32,3x3,SAME)+bias+ReLU+maxpool2 per image.
// Two 34-row halves in 29KB LDS (4+ blocks/CU). Weights via wave-uniform
// global reads -> scalar loads (SMEM pipe), no LDS weight traffic.
// Output: X1 bf16 [img][y(32)][x(32)][ic(32)]
// ---------------------------------------------------------------------------
#define C1P 72
__global__ __launch_bounds__(256) void conv1_k(
    const float* __restrict__ video, const float* __restrict__ w1,
    const float* __restrict__ b1, unsigned short* __restrict__ X1)
{
  __shared__ float imgs[3 * 34 * C1P];   // 29376 B
  const int img = blockIdx.x, t = threadIdx.x;
  const float* vin = video + (size_t)img * 12288;
  const int px = t & 31, pyl = t >> 5;

#pragma unroll 1
  for (int h = 0; h < 2; ++h) {
    __syncthreads();
    float4 z4 = {0.f, 0.f, 0.f, 0.f};
    for (int i = t; i < (3 * 34 * C1P) / 4; i += 256) ((float4*)imgs)[i] = z4;
    __syncthreads();
    // stage 33 valid rows per half (h=0: gr 0..32 -> r 1..33; h=1: gr 31..63 -> r 0..32)
    for (int i = t; i < 3 * 33 * 16; i += 256) {
      int ic = i / 528; int rr = (i - ic * 528) >> 4; int c4 = i & 15;
      int r  = rr + (h ? 0 : 1);
      int gr = 32 * h - 1 + r;
      float4 v = *(const float4*)(vin + ic * 4096 + gr * 64 + c4 * 4);
      *(float4*)(imgs + ic * (34 * C1P) + r * C1P + 4 + c4 * 4) = v;
    }
    __syncthreads();
#pragma unroll 1
    for (int s = 0; s < 2; ++s) {
      const int y = pyl + 8 * (2 * h + s);   // pooled row 0..31
      const int lr0 = 2 * (pyl + 8 * s);     // local window row base
      float in[3][4][4];
#pragma unroll
      for (int ic = 0; ic < 3; ++ic)
#pragma unroll
        for (int rr = 0; rr < 4; ++rr)
#pragma unroll
          for (int cc = 0; cc < 4; ++cc)
            in[ic][rr][cc] = imgs[ic * (34 * C1P) + (lr0 + rr) * C1P + (2 * px + 3 + cc)];
      unsigned ob[16];
#pragma unroll 1
      for (int ch = 0; ch < 32; ++ch) {
        float wv[27];
#pragma unroll
        for (int j = 0; j < 27; ++j) wv[j] = w1[ch * 27 + j];   // uniform -> s_load
        float bb = b1[ch];
        float a0 = bb, a1 = bb, a2 = bb, a3 = bb;
#pragma unroll
        for (int ic = 0; ic < 3; ++ic)
#pragma unroll
          for (int dy = 0; dy < 3; ++dy)
#pragma unroll
            for (int dx = 0; dx < 3; ++dx) {
              float w = wv[ic * 9 + dy * 3 + dx];
              a0 = fmaf(w, in[ic][dy    ][dx    ], a0);
              a1 = fmaf(w, in[ic][dy    ][dx + 1], a1);
              a2 = fmaf(w, in[ic][dy + 1][dx    ], a2);
              a3 = fmaf(w, in[ic][dy + 1][dx + 1], a3);
            }
        a0 = fmaxf(a0, 0.f); a1 = fmaxf(a1, 0.f);
        a2 = fmaxf(a2, 0.f); a3 = fmaxf(a3, 0.f);
        float pooled = fmaxf(fmaxf(a0, a1), fmaxf(a2, a3));
        unsigned short u = f2bf(pooled);
        if ((ch & 1) == 0) ob[ch >> 1] = (unsigned)u;
        else               ob[ch >> 1] |= ((unsigned)u << 16);
      }
      size_t base = ((size_t)img * 1024 + (size_t)y * 32 + px) * 32;
      uint4* dst = (uint4*)(X1 + base);
      uint4 o0 = {ob[0], ob[1], ob[2], ob[3]};
      uint4 o1 = {ob[4], ob[5], ob[6], ob[7]};
      uint4 o2 = {ob[8], ob[9], ob[10], ob[11]};
      uint4 o3 = {ob[12], ob[13], ob[14], ob[15]};
      dst[0] = o0; dst[1] = o1; dst[2] = o2; dst[3] = o3;
    }
  }
}

// ---------------------------------------------------------------------------
// conv2_k: implicit-GEMM conv(32->64)+bias+ReLU+maxpool2+mean via MFMA.
// ---------------------------------------------------------------------------
#define X_LDS_BYTES (4 * 1156 * 16)   // 73984
#define OCT_STRIDE  (1156 * 16)
__global__ __launch_bounds__(256) void conv2_k(
    const unsigned short* __restrict__ X1, const unsigned short* __restrict__ Wb,
    const float* __restrict__ b2, float* __restrict__ feat)
{
  extern __shared__ char sm[];
  float* part = (float*)(sm + X_LDS_BYTES);
  const int img = blockIdx.x, t = threadIdx.x;
  const int lane = t & 63, wv = t >> 6;
  const int kg = lane >> 4, l15 = lane & 15;

  for (int j = t; j < 1156; j += 256) {
    int r = j / 34, cc = j - r * 34;
    if (r == 0 || r == 33 || cc == 0 || cc == 33) {
      uint4 z = {0, 0, 0, 0};
#pragma unroll
      for (int oct = 0; oct < 4; ++oct)
        *(uint4*)(sm + oct * OCT_STRIDE + j * 16) = z;
    }
  }
  const uint4* src = (const uint4*)(X1 + (size_t)img * 32768);
#pragma unroll 4
  for (int i = 0; i < 16; ++i) {
    int c = i * 256 + t;
    uint4 v = src[c];
    int oct = c & 3, P = c >> 2;
    int y = P >> 5, x = P & 31;
    *(uint4*)(sm + oct * OCT_STRIDE + ((y + 1) * 34 + (x + 1)) * 16) = v;
  }
  __syncthreads();

  float bia[4][4];
#pragma unroll
  for (int mt = 0; mt < 4; ++mt)
#pragma unroll
    for (int r = 0; r < 4; ++r) bia[mt][r] = b2[mt * 16 + kg * 4 + r];

  float msum[4][4];
#pragma unroll
  for (int mt = 0; mt < 4; ++mt)
#pragma unroll
    for (int r = 0; r < 4; ++r) msum[mt][r] = 0.f;

#pragma unroll 1
  for (int pass = 0; pass < 2; ++pass) {
    f32x4 acc[4][8];
#pragma unroll
    for (int mt = 0; mt < 4; ++mt)
#pragma unroll
      for (int q = 0; q < 8; ++q) acc[mt][q] = (f32x4){0.f, 0.f, 0.f, 0.f};
    int Pq[8];
#pragma unroll
    for (int q = 0; q < 8; ++q) {
      int p = (wv * 16 + pass * 8 + q) * 16 + l15;
      int y = p >> 5, x = p & 31;
      Pq[q] = y * 34 + x;
    }
#pragma unroll
    for (int sh = 0; sh < 9; ++sh) {
      const int dy = sh / 3, dx = sh % 3;
      const int shoff = (dy * 34 + dx) * 16;
      short8v Af[4];
#pragma unroll
      for (int mt = 0; mt < 4; ++mt)
        Af[mt] = *(const short8v*)(Wb + ((size_t)(sh * 4 + mt) * 64 + lane) * 8);
#pragma unroll
      for (int q = 0; q < 8; ++q) {
        short8v Bf = *(const short8v*)(sm + kg * OCT_STRIDE + Pq[q] * 16 + shoff);
#pragma unroll
        for (int mt = 0; mt < 4; ++mt)
          acc[mt][q] = __builtin_amdgcn_mfma_f32_16x16x32_bf16(Af[mt], Bf, acc[mt][q], 0, 0, 0);
      }
    }
#pragma unroll
    for (int mt = 0; mt < 4; ++mt) {
#pragma unroll
      for (int pr = 0; pr < 4; ++pr) {
        int qa = (pr & 1) + (pr >> 1) * 4;
        int qb = qa + 2;
#pragma unroll
        for (int r = 0; r < 4; ++r) {
          float va = fmaxf(acc[mt][qa][r] + bia[mt][r], 0.f);
          float vb = fmaxf(acc[mt][qb][r] + bia[mt][r], 0.f);
          float v = fmaxf(va, vb);
          v = fmaxf(v, __shfl_xor(v, 1, 64));
          msum[mt][r] += v;
        }
      }
    }
  }
#pragma unroll
  for (int mt = 0; mt < 4; ++mt)
#pragma unroll
    for (int r = 0; r < 4; ++r) {
      float v = msum[mt][r];
      v += __shfl_xor(v, 1, 64);
      v += __shfl_xor(v, 2, 64);
      v += __shfl_xor(v, 4, 64);
      v += __shfl_xor(v, 8, 64);
      if (l15 == 0) part[wv * 64 + mt * 16 + kg * 4 + r] = v * 0.5f;
    }
  __syncthreads();
  if (t < 64)
    feat[(size_t)img * 64 + t] =
        (part[t] + part[64 + t] + part[128 + t] + part[192 + t]) * (1.f / 256.f);
}

// ---------------------------------------------------------------------------
// Generic f32 GEMM, templated M-tile (64 or 32). C = act(A@B^T + bias) [+C]
// ---------------------------------------------------------------------------
struct GemmArgs {
  const float* A0; const float* A1;
  const float* B0; const float* B1;
  const float* bias0; const float* bias1;
  float* C0; float* C1;
  int M, N, K, lda, ldb, ldc, act, resid;
};

template <int TM>
__global__ __launch_bounds__(256) void gemm_bt(GemmArgs g) {
  constexpr int RM = TM / 16;        // rows staged per thread / micro rows
  const int dir = blockIdx.z;
  const float* __restrict__ A = dir ? g.A1 : g.A0;
  const float* __restrict__ B = dir ? g.B1 : g.B0;
  const float* bias = dir ? g.bias1 : g.bias0;
  float* __restrict__ C = dir ? g.C1 : g.C0;
  __shared__ float sA[16][TM + 4];
  __shared__ float sB[16][68];
  const int t = threadIdx.x;
  const int m0 = blockIdx.x * TM;
  const int n0 = blockIdx.y * 64;
  const int tx = t & 15, ty = t >> 4;
  const int lk = t & 15, lr = t >> 4;
  float acc[RM][4] = {};
  for (int k0 = 0; k0 < g.K; k0 += 16) {
    bool kok = (k0 + lk) < g.K;
#pragma unroll
    for (int rr = 0; rr < RM; ++rr) {
      int m = m0 + lr + rr * 16;
      sA[lk][lr + rr * 16] = (kok && m < g.M) ? A[(size_t)m * g.lda + k0 + lk] : 0.f;
    }
#pragma unroll
    for (int rr = 0; rr < 4; ++rr) {
      int n = n0 + lr + rr * 16;
      sB[lk][lr + rr * 16] = (kok && n < g.N) ? B[(size_t)n * g.ldb + k0 + lk] : 0.f;
    }
    __syncthreads();
#pragma unroll
    for (int kk = 0; kk < 16; ++kk) {
      float av[RM];
#pragma unroll
      for (int i = 0; i < RM; ++i) av[i] = sA[kk][ty * RM + i];
      float b0 = sB[kk][tx*4+0], b1 = sB[kk][tx*4+1], b2 = sB[kk][tx*4+2], b3 = sB[kk][tx*4+3];
#pragma unroll
      for (int i = 0; i < RM; ++i) {
        acc[i][0] = fmaf(av[i], b0, acc[i][0]);
        acc[i][1] = fmaf(av[i], b1, acc[i][1]);
        acc[i][2] = fmaf(av[i], b2, acc[i][2]);
        acc[i][3] = fmaf(av[i], b3, acc[i][3]);
      }
    }
    __syncthreads();
  }
#pragma unroll
  for (int i = 0; i < RM; ++i) {
    int m = m0 + ty * RM + i;
    if (m >= g.M) continue;
#pragma unroll
    for (int j = 0; j < 4; ++j) {
      int n = n0 + tx * 4 + j;
      if (n >= g.N) continue;
      float v = acc[i][j];
      if (bias) v += bias[n];
      if (g.act == 1) v = v / (1.f + __expf(-v));
      else if (g.act == 2) v = (v > 20.f) ? v : log1pf(expf(v));
      size_t ci = (size_t)m * g.ldc + n;
      if (g.resid) v += C[ci];
      C[ci] = v;
    }
  }
}

// ---------------------------------------------------------------------------
// small kernels
// ---------------------------------------------------------------------------
__global__ void audio_concat(const float* __restrict__ audio, float* __restrict__ xc0) {
  int i = blockIdx.x*256 + threadIdx.x;
  if (i >= BATCH*FRAMES*NM) return;
  int j = i % NM; int f = (i / NM) % FRAMES; int b = i / (NM*FRAMES);
  xc0[(size_t)(b*FRAMES + f)*DD + VF + j] = audio[(size_t)b*(FRAMES*NM) + f*NM + j];
}

__global__ void copy_rev(const float* __restrict__ src, float* __restrict__ xf, float* __restrict__ xr) {
  int i = blockIdx.x*256 + threadIdx.x;
  if (i >= TOK*DD) return;
  int d = i % DD; int tok = i / DD; int b = tok / FRAMES; int l = tok % FRAMES;
  float v = src[i];
  xf[i] = v;
  xr[(size_t)(b*FRAMES + (FRAMES-1-l))*DD + d] = v;
}

__global__ __launch_bounds__(64) void rmsnorm_k(
    const float* __restrict__ xF, const float* __restrict__ xR,
    const float* __restrict__ wF, const float* __restrict__ wR,
    float* __restrict__ oF, float* __restrict__ oR)
{
  const int dir = blockIdx.y;
  const float* x = (dir ? xR : xF) + (size_t)blockIdx.x * DD;
  const float* w = dir ? wR : wF;
  float* o = (dir ? oR : oF) + (size_t)blockIdx.x * DD;
  int t = threadIdx.x;
  float v0 = x[t], v1 = x[t+64], v2 = x[t+128], v3 = x[t+192];
  float ss = v0*v0 + v1*v1 + v2*v2 + v3*v3;
#pragma unroll
  for (int off = 32; off; off >>= 1) ss += __shfl_xor(ss, off, 64);
  float r = rsqrtf(ss * (1.f/DD) + 1e-5f);
  o[t]     = v0*r*w[t];
  o[t+64]  = v1*r*w[t+64];
  o[t+128] = v2*r*w[t+128];
  o[t+192] = v3*r*w[t+192];
}

__global__ void convsilu_k(const float* __restrict__ xzF, const float* __restrict__ xzR,
                           const float* __restrict__ cwF, const float* __restrict__ cwR,
                           const float* __restrict__ cbF, const float* __restrict__ cbR,
                           float* __restrict__ oF, float* __restrict__ oR) {
  const int dir = blockIdx.z;
  const float* xz = dir ? xzR : xzF;
  const float* cw = dir ? cwR : cwF;
  const float* cb = dir ? cbR : cbF;
  float* o = dir ? oR : oF;
  int i = blockIdx.x*256 + threadIdx.x;
  if (i >= TOK*EDIM) return;
  int e   = i & (EDIM-1);
  int tok = i >> 9;
  int l   = tok & (FRAMES-1);
  float4 cv = ((const float4*)cw)[e];
  float acc = cb[e];
  const float* xcol = xz + (size_t)tok*1024 + e;
  if (l >= 3) acc = fmaf(xcol[-3*1024], cv.x, acc);
  if (l >= 2) acc = fmaf(xcol[-2*1024], cv.y, acc);
  if (l >= 1) acc = fmaf(xcol[-1*1024], cv.z, acc);
  acc = fmaf(xcol[0], cv.w, acc);
  o[i] = acc / (1.f + __expf(-acc));
}

// ---------------------------------------------------------------------------
// scan2_k: state-parallel selective scan. 16 lanes per (b,e) chain, one state
// per lane; db tile staged in LDS; y via width-16 shfl_xor reduce.
// grid (256,1,2), block 256.
// ---------------------------------------------------------------------------
__global__ __launch_bounds__(256) void scan2_k(
    const float* __restrict__ xzF, const float* __restrict__ xzR,
    const float* __restrict__ xcF, const float* __restrict__ xcR,
    const float* __restrict__ dbF, const float* __restrict__ dbR,
    const float* __restrict__ dlF, const float* __restrict__ dlR,
    const float* __restrict__ AlF, const float* __restrict__ AlR,
    const float* __restrict__ DpF, const float* __restrict__ DpR,
    float* __restrict__ yF, float* __restrict__ yR)
{
  const int dir = blockIdx.z;
  const float* xz = dir ? xzR : xzF;
  const float* xc = dir ? xcR : xcF;
  const float* db = dir ? dbR : dbF;
  const float* dl = dir ? dlR : dlF;
  const float* Al = dir ? AlR : AlF;
  const float* Dp = dir ? DpR : DpF;
  float* y = dir ? yR : yF;

  __shared__ float sdb[FRAMES * 48];   // 24KB
  const int b  = blockIdx.x >> 5;
  const int e0 = (blockIdx.x & 31) << 4;
  const int t = threadIdx.x;
  const int g = t >> 4, n = t & 15;
  const int e = e0 + g;

  const float* dbp = db + (size_t)b * FRAMES * 48;
  for (int i = t; i < FRAMES * 48 / 4; i += 256)
    ((float4*)sdb)[i] = ((const float4*)dbp)[i];

  float An = -expf(Al[e * NSTATE + n]);
  float Dv = Dp[e];
  float h = 0.f;
  const float* dlp = dl + (size_t)b * FRAMES * EDIM + e;
  const float* xcp = xc + (size_t)b * FRAMES * EDIM + e;
  const float* zp  = xz + (size_t)b * FRAMES * 1024 + 512 + e;
  float* yp = y + (size_t)b * FRAMES * EDIM + e;
  __syncthreads();

#pragma unroll 1
  for (int l = 0; l < FRAMES; ++l) {
    float dlt = dlp[(size_t)l * EDIM];
    float xcv = xcp[(size_t)l * EDIM];
    float zz  = zp[(size_t)l * 1024];
    float Bn = sdb[l * 48 + 16 + n];
    float Cn = sdb[l * 48 + 32 + n];
    float dA = __expf(dlt * An);
    h = fmaf(dA, h, dlt * xcv * Bn);
    float part = h * Cn;
    part += __shfl_xor(part, 1, 16);
    part += __shfl_xor(part, 2, 16);
    part += __shfl_xor(part, 4, 16);
    part += __shfl_xor(part, 8, 16);
    if (n == 0) {
      float acc = fmaf(Dv, xcv, part);
      float sz = zz / (1.f + __expf(-zz));
      yp[(size_t)l * EDIM] = acc * sz;
    }
  }
}

__global__ __launch_bounds__(256) void head_k(
    const float* __restrict__ xf, const float* __restrict__ xr,
    const float* __restrict__ fcw, const float* __restrict__ fcb,
    const float* __restrict__ fc2w, const float* __restrict__ fc2b,
    float* __restrict__ out)
{
  int b = blockIdx.x;
  __shared__ float xl[2*DD];
  __shared__ float h[DD];
  int t = threadIdx.x;
  xl[t]      = xf[(size_t)(b*FRAMES + FRAMES-1)*DD + t];
  xl[DD + t] = xr[(size_t)(b*FRAMES + 0)*DD + t];
  __syncthreads();
  float acc = fcb[t];
  for (int k = 0; k < 2*DD; ++k) acc = fmaf(xl[k], fcw[(size_t)t*2*DD + k], acc);
  h[t] = acc;
  __syncthreads();
  if (t < 2) {
    float a = fc2b[t];
    for (int k = 0; k < DD; ++k) a = fmaf(h[k], fc2w[(size_t)t*DD + k], a);
    out[b*2 + t] = a;
  }
}

// ---------------------------------------------------------------------------
extern "C" void kernel_launch(void* const* d_in, const int* in_sizes, int n_in,
                              void* d_out, int out_size, void* d_ws, size_t ws_size,
                              hipStream_t stream) {
  const float* video = (const float*)d_in[0];
  const float* audio = (const float*)d_in[1];
  const float* c1w = (const float*)d_in[2];
  const float* c1b = (const float*)d_in[3];
  const float* c2w = (const float*)d_in[4];
  const float* c2b = (const float*)d_in[5];
  const float* fcw = (const float*)d_in[6];
  const float* fcb = (const float*)d_in[7];
  const float* Wf[10]; const float* Wb_[10];
  for (int i = 0; i < 10; ++i) { Wf[i] = (const float*)d_in[8+i]; Wb_[i] = (const float*)d_in[18+i]; }
  const float* fc_w  = (const float*)d_in[28];
  const float* fc_b  = (const float*)d_in[29];
  const float* fc2_w = (const float*)d_in[30];
  const float* fc2_b = (const float*)d_in[31];
  float* out = (float*)d_out;

  float* ws   = (float*)d_ws;
  float* feat = ws;
  float* xc0  = feat + 65536;
  float* xf   = xc0  + 262144;
  float* xr   = xf   + 262144;
  float* xnF  = xr   + 262144;
  float* xnR  = xnF  + 262144;
  float* xzF  = xnR  + 262144;
  float* xzR  = xzF  + 1048576;
  float* xvF  = xzR  + 1048576;
  float* xvR  = xvF  + 524288;
  float* dbF  = xvR  + 524288;
  float* dbR  = dbF  + 49152;
  float* dlF  = dbR  + 49152;
  float* dlR  = dlF  + 524288;
  float* ybF  = dlR  + 524288;
  float* ybR  = ybF  + 524288;
  unsigned short* X1 = (unsigned short*)(ws + 6717440);
  unsigned short* Wbp = (unsigned short*)(ws + 6717440 + 16777216);

  // 1. CNN
  pack_w2<<<dim3(9), 256, 0, stream>>>(c2w, Wbp);
  conv1_k<<<dim3(TOK), 256, 0, stream>>>(video, c1w, c1b, X1);
  conv2_k<<<dim3(TOK), 256, (size_t)(X_LDS_BYTES + 1024), stream>>>(X1, Wbp, c2b, feat);

  // 2. cnn fc + concat + reverse
  { GemmArgs g{feat, feat, fcw, fcw, fcb, fcb, xc0, xc0, TOK, VF, 64, 64, 64, DD, 0, 0};
    gemm_bt<64><<<dim3(16, 4, 1), 256, 0, stream>>>(g); }
  audio_concat<<<dim3((BATCH*FRAMES*NM + 255)/256), 256, 0, stream>>>(audio, xc0);
  copy_rev<<<dim3((TOK*DD + 255)/256), 256, 0, stream>>>(xc0, xf, xr);

  // 3. bi-Mamba
  for (int l = 0; l < NLAYER; ++l) {
    const float* nwF  = Wf[0] + l*DD;              const float* nwR  = Wb_[0] + l*DD;
    const float* ipF  = Wf[1] + (size_t)l*1024*DD; const float* ipR  = Wb_[1] + (size_t)l*1024*DD;
    const float* cwF_ = Wf[2] + l*EDIM*4;          const float* cwR_ = Wb_[2] + l*EDIM*4;
    const float* cbF_ = Wf[3] + l*EDIM;            const float* cbR_ = Wb_[3] + l*EDIM;
    const float* xpF  = Wf[4] + l*48*EDIM;         const float* xpR  = Wb_[4] + l*48*EDIM;
    const float* dwF  = Wf[5] + l*EDIM*DTRANK;     const float* dwR  = Wb_[5] + l*EDIM*DTRANK;
    const float* dbF_ = Wf[6] + l*EDIM;            const float* dbR_ = Wb_[6] + l*EDIM;
    const float* AlF  = Wf[7] + l*EDIM*NSTATE;     const float* AlR  = Wb_[7] + l*EDIM*NSTATE;
    const float* DpF  = Wf[8] + l*EDIM;            const float* DpR  = Wb_[8] + l*EDIM;
    const float* opF  = Wf[9] + (size_t)l*DD*EDIM; const float* opR  = Wb_[9] + (size_t)l*DD*EDIM;

    rmsnorm_k<<<dim3(TOK, 2), 64, 0, stream>>>(xf, xr, nwF, nwR, xnF, xnR);
    { GemmArgs g{xnF, xnR, ipF, ipR, nullptr, nullptr, xzF, xzR, TOK, 1024, DD, DD, DD, 1024, 0, 0};
      gemm_bt<64><<<dim3(16,16,2), 256, 0, stream>>>(g); }
    convsilu_k<<<dim3(TOK*EDIM/256, 1, 2), 256, 0, stream>>>(xzF, xzR, cwF_, cwR_, cbF_, cbR_, xvF, xvR);
    { GemmArgs g{xvF, xvR, xpF, xpR, nullptr, nullptr, dbF, dbR, TOK, 48, EDIM, EDIM, EDIM, 48, 0, 0};
      gemm_bt<32><<<dim3(32,1,2), 256, 0, stream>>>(g); }
    { GemmArgs g{dbF, dbR, dwF, dwR, dbF_, dbR_, dlF, dlR, TOK, EDIM, DTRANK, 48, DTRANK, EDIM, 2, 0};
      gemm_bt<64><<<dim3(16,8,2), 256, 0, stream>>>(g); }
    scan2_k<<<dim3(256,1,2), 256, 0, stream>>>(xzF, xzR, xvF, xvR, dbF, dbR, dlF, dlR, AlF, AlR, DpF, DpR, ybF, ybR);
    { GemmArgs g{ybF, ybR, opF, opR, nullptr, nullptr, xf, xr, TOK, DD, EDIM, EDIM, EDIM, DD, 0, 1};
      gemm_bt<32><<<dim3(32,4,2), 256, 0, stream>>>(g); }
  }

  // 4. head
  head_k<<<dim3(BATCH), 256, 0, stream>>>(xf, xr, fc_w, fc_b, fc2_w, fc2_b, out);
}